// Round 1
// baseline (573.029 us; speedup 1.0000x reference)
//
#include <hip/hip_runtime.h>

#define NB 32
#define NN 128
#define NC 16

// 15 (l, pair) entries in reference order:
// l=0: (0,0),(1,1),(2,2)
// l=1: (0,1),(1,0),(1,1),(1,2),(2,1),(2,2)
// l=2: (0,2),(1,1),(1,2),(2,0),(2,1),(2,2)
__constant__ int E_l [15] = {0,0,0, 1,1,1,1,1,1, 2,2,2,2,2,2};
__constant__ int E_l1[15] = {0,1,2, 0,1,1,1,2,2, 0,1,1,2,2,2};
__constant__ int E_l2[15] = {0,1,2, 1,0,1,2,1,2, 2,1,2,0,1,2};
__constant__ int E_cg[15] = {0,1,10, 35,44,53,80,125,170, 245,270,315,390,415,490};
__constant__ int E_t [15] = {0,16,32, 48,96,144,192,240,288, 336,416,496,576,656,736};

__device__ __forceinline__ int lbase(int l){ return l==0?0:(l==1?1:4); }

__device__ __forceinline__ double dfact(int n){
    const double F[9] = {1.0,1.0,2.0,6.0,24.0,120.0,720.0,5040.0,40320.0};
    return F[n];
}

__device__ float cg_single(int j1,int m1,int j2,int m2,int j,int m){
    if (m1 + m2 != m) return 0.0f;
    double pre = sqrt((2.0*j+1.0)*dfact(j+j1-j2)*dfact(j-j1+j2)*dfact(j1+j2-j)/dfact(j1+j2+j+1));
    pre *= sqrt(dfact(j+m)*dfact(j-m)*dfact(j1-m1)*dfact(j1+m1)*dfact(j2-m2)*dfact(j2+m2));
    int k0 = 0;
    if (j2-j-m1 > k0) k0 = j2-j-m1;
    if (j1+m2-j > k0) k0 = j1+m2-j;
    int k1 = j1+j2-j;
    if (j1-m1 < k1) k1 = j1-m1;
    if (j2+m2 < k1) k1 = j2+m2;
    double s = 0.0;
    for (int k = k0; k <= k1; ++k){
        double d = dfact(k)*dfact(j1+j2-j-k)*dfact(j1-m1-k)*dfact(j2+m2-k)*dfact(j-j2+m1+k)*dfact(j-j1-m2+k);
        s += ((k & 1) ? -1.0 : 1.0) / d;
    }
    return (float)(pre * s);
}

// Fill 615-entry CG table (layout: 15 entries, each (2l1+1)*(2l2+1)*(2l+1), idx = (i1*(2l2+1)+u)*(2l+1)+k)
__global__ void k_cg(float* __restrict__ cg){
    for (int idx = threadIdx.x; idx < 615; idx += blockDim.x){
        int e = 0;
        while (e < 14 && idx >= E_cg[e+1]) e++;
        int l = E_l[e], l1 = E_l1[e], l2 = E_l2[e];
        int local = idx - E_cg[e];
        int dl = 2*l+1, d2 = 2*l2+1;
        int k  = local % dl;
        int r  = local / dl;
        int u  = r % d2;
        int i1 = r / d2;
        cg[idx] = cg_single(l1, i1-l1, l2, u-l2, l, k-l);
    }
}

// WrSum[layer][row][co] = sum_d Wr[l][layer][pair*256 + c*16 + d][co], row = rowbase(l)+pair*16+c
// per-layer stride 240*16 = 3840
__global__ void k_wrsum(const float* __restrict__ Wr0, const float* __restrict__ Wr1,
                        const float* __restrict__ Wr2, float* __restrict__ wrsum){
    int q = blockIdx.x * blockDim.x + threadIdx.x;
    if (q >= 7680) return;
    int layer = q / 3840;
    int r = q % 3840;
    int row = r / 16, co = r % 16;
    const float* Wr; int pairs; int lrow;
    if (row < 48)       { Wr = Wr0; pairs = 3; lrow = row; }
    else if (row < 144) { Wr = Wr1; pairs = 6; lrow = row - 48; }
    else                { Wr = Wr2; pairs = 6; lrow = row - 144; }
    int pairIdx = lrow / 16, c = lrow % 16;
    const float* base = Wr + (size_t)layer * pairs * 256 * 16 + (size_t)(pairIdx*256 + c*16) * 16 + co;
    float s = 0.f;
    #pragma unroll
    for (int d = 0; d < 16; ++d) s += base[d * 16];
    wrsum[q] = s;
}

// sphx[node][0..8] = sum_j Y(rel_pos[node][j])
__global__ __launch_bounds__(64) void k_sphx(const float* __restrict__ rel_pos, float* __restrict__ sphx){
    int node = blockIdx.x;
    int t = threadIdx.x;
    const float* rp = rel_pos + (size_t)node * NN * 3;
    float acc[9];
    #pragma unroll
    for (int i = 0; i < 9; ++i) acc[i] = 0.f;
    for (int j = t; j < NN; j += 64){
        float x = rp[j*3+0], y = rp[j*3+1], z = rp[j*3+2];
        float r = sqrtf(x*x + y*y + z*z) + 1e-6f;
        x /= r; y /= r; z /= r;
        acc[0] += 0.28209479f;
        acc[1] += 0.48860251f * y;
        acc[2] += 0.48860251f * z;
        acc[3] += 0.48860251f * x;
        acc[4] += 1.09254843f * x * y;
        acc[5] += 1.09254843f * y * z;
        acc[6] += 0.31539157f * (3.f * z * z - 1.f);
        acc[7] += 1.09254843f * x * z;
        acc[8] += 0.54627422f * (x*x - y*y);
    }
    #pragma unroll
    for (int i = 0; i < 9; ++i){
        float v = acc[i];
        for (int off = 32; off; off >>= 1) v += __shfl_down(v, off, 64);
        if (t == 0) sphx[node*9 + i] = v;
    }
}

// Per node: T[l][pair][k][c] = sum_m verts[l1][m][c] * (sum_u sphx[l2][u]*cg[m,u,k]);
// rel[node][krow*16+co] = sum_{pair,c} T * WrSum
__global__ __launch_bounds__(64) void k_rel(const float* __restrict__ p0, const float* __restrict__ p1,
                                            const float* __restrict__ p2, int s0, int s1, int s2,
                                            const float* __restrict__ sphx, const float* __restrict__ cgT,
                                            const float* __restrict__ wrsumL, float* __restrict__ rel){
    __shared__ float A[144];
    __shared__ float S[16];
    __shared__ float CG[615];
    __shared__ float T[816];
    int node = blockIdx.x;
    int t = threadIdx.x;
    for (int i = t; i < 615; i += 64) CG[i] = cgT[i];
    for (int i = t; i < 144; i += 64){
        float v;
        if (i < 16)      v = p0[(size_t)node*s0 + i];
        else if (i < 64) v = p1[(size_t)node*s1 + (i-16)];
        else             v = p2[(size_t)node*s2 + (i-64)];
        A[i] = v;
    }
    if (t < 9) S[t] = sphx[node*9 + t];
    __syncthreads();
    for (int idx = t; idx < 816; idx += 64){
        int e = 0;
        while (e < 14 && idx >= E_t[e+1]) e++;
        int l = E_l[e], l1 = E_l1[e], l2 = E_l2[e];
        int local = idx - E_t[e];
        int c = local & 15, k = local >> 4;
        int d2 = 2*l2+1, dl = 2*l+1;
        const float* cge = &CG[E_cg[e]];
        int ab = lbase(l1), sb = lbase(l2);
        float s = 0.f;
        for (int m = 0; m < 2*l1+1; ++m){
            float g = 0.f;
            for (int u = 0; u < d2; ++u) g += S[sb+u] * cge[(m*d2+u)*dl + k];
            s += A[(ab+m)*16 + c] * g;
        }
        T[idx] = s;
    }
    __syncthreads();
    for (int o = t; o < 144; o += 64){
        int krow = o >> 4, co = o & 15;
        int l = krow == 0 ? 0 : (krow < 4 ? 1 : 2);
        int k = krow - (l == 0 ? 0 : (l == 1 ? 1 : 4));
        int np = l == 0 ? 3 : 6;
        int tb = l == 0 ? 0 : (l == 1 ? 48 : 336);
        int rb = l == 0 ? 0 : (l == 1 ? 48 : 144);
        int dl = 2*l+1;
        float acc = 0.f;
        for (int p = 0; p < np; ++p){
            const float* Tp = &T[tb + p*dl*16 + k*16];
            const float* W  = &wrsumL[(size_t)(rb + p*16) * 16 + co];
            #pragma unroll
            for (int c = 0; c < 16; ++c) acc += Tp[c] * W[c*16];
        }
        rel[(size_t)node*144 + o] = acc;
    }
}

// Per node i: mp = sum_j conn[i,j]*rel[j]; cg_nl diag product; nl = cg_nl * Wn; atomic ss per l
__global__ __launch_bounds__(64) void k_mpnl(const float* __restrict__ norms, const float* __restrict__ rel,
                                             const float* __restrict__ cgT,
                                             const float* __restrict__ Wn0, const float* __restrict__ Wn1,
                                             const float* __restrict__ Wn2,
                                             int layer, float* __restrict__ nl, float* __restrict__ ss){
    __shared__ float conn[128];
    __shared__ float mp[144];
    __shared__ float CG[615];
    __shared__ float T[816];
    int node = blockIdx.x;
    int b = node >> 7;
    int t = threadIdx.x;
    for (int i = t; i < 615; i += 64) CG[i] = cgT[i];
    const float* nr = norms + (size_t)node * NN;
    for (int j = t; j < NN; j += 64) conn[j] = (nr[j] < 0.5f) ? 1.f : 0.f;
    __syncthreads();
    const float* relb = rel + (size_t)b * NN * 144;
    for (int o = t; o < 144; o += 64){
        float acc = 0.f;
        for (int j = 0; j < NN; ++j) acc += conn[j] * relb[(size_t)j*144 + o];
        mp[o] = acc;
    }
    __syncthreads();
    for (int idx = t; idx < 816; idx += 64){
        int e = 0;
        while (e < 14 && idx >= E_t[e+1]) e++;
        int l = E_l[e], l1 = E_l1[e], l2 = E_l2[e];
        int local = idx - E_t[e];
        int c = local & 15, k = local >> 4;
        int d2 = 2*l2+1, dl = 2*l+1;
        const float* cge = &CG[E_cg[e]];
        int ab = lbase(l1), bb = lbase(l2);
        float s = 0.f;
        for (int m = 0; m < 2*l1+1; ++m){
            float am = mp[(ab+m)*16 + c];
            for (int u = 0; u < d2; ++u) s += am * mp[(bb+u)*16 + c] * cge[(m*d2+u)*dl + k];
        }
        T[idx] = s;
    }
    __syncthreads();
    float pz0 = 0.f, pz1 = 0.f, pz2 = 0.f;
    for (int o = t; o < 144; o += 64){
        int krow = o >> 4, co = o & 15;
        int l = krow == 0 ? 0 : (krow < 4 ? 1 : 2);
        int k = krow - (l == 0 ? 0 : (l == 1 ? 1 : 4));
        int np = l == 0 ? 3 : 6;
        int tb = l == 0 ? 0 : (l == 1 ? 48 : 336);
        int dl = 2*l+1;
        const float* Wn = (l == 0) ? Wn0 : (l == 1 ? Wn1 : Wn2);
        const float* Wl = Wn + (size_t)layer * np * 16 * 16 + co;
        float acc = 0.f;
        for (int p = 0; p < np; ++p){
            const float* Tp = &T[tb + p*dl*16 + k*16];
            #pragma unroll
            for (int c = 0; c < 16; ++c) acc += Tp[c] * Wl[(size_t)(p*16 + c) * 16];
        }
        nl[(size_t)node*144 + o] = acc;
        float sq = acc * acc;
        if (l == 0) pz0 += sq; else if (l == 1) pz1 += sq; else pz2 += sq;
    }
    for (int off = 32; off; off >>= 1){
        pz0 += __shfl_down(pz0, off, 64);
        pz1 += __shfl_down(pz1, off, 64);
        pz2 += __shfl_down(pz2, off, 64);
    }
    if (t == 0){
        atomicAdd(&ss[0], pz0);
        atomicAdd(&ss[1], pz1);
        atomicAdd(&ss[2], pz2);
    }
}

// Normalize in place (nl becomes verts) and emit scalars for this layer
__global__ __launch_bounds__(64) void k_norm(float* __restrict__ nl, const float* __restrict__ ss,
                                             float* __restrict__ out, int layer){
    __shared__ float vv[144];
    __shared__ float sc[3];
    int node = blockIdx.x;
    int t = threadIdx.x;
    if (t < 3) sc[t] = 16.f / ((2*t + 1) * sqrtf(ss[t]));
    __syncthreads();
    for (int i = t; i < 144; i += 64){
        int krow = i >> 4;
        int l = krow == 0 ? 0 : (krow < 4 ? 1 : 2);
        float v = nl[(size_t)node*144 + i] * sc[l];
        vv[i] = v;
        nl[(size_t)node*144 + i] = v;
    }
    __syncthreads();
    if (t < 16){
        int c = t;
        float s0 = vv[c];
        float sn0 = s0 * s0;
        float sn1 = 0.f;
        #pragma unroll
        for (int k = 0; k < 3; ++k){ float v = vv[16 + k*16 + c]; sn1 += v*v; }
        float sn2 = 0.f;
        #pragma unroll
        for (int k = 0; k < 5; ++k){ float v = vv[64 + k*16 + c]; sn2 += v*v; }
        float* ob = out + (size_t)node * 128 + layer * 64;
        ob[c]      = s0;
        ob[16 + c] = sn0;
        ob[32 + c] = sn1;
        ob[48 + c] = sn2;
    }
}

extern "C" void kernel_launch(void* const* d_in, const int* in_sizes, int n_in,
                              void* d_out, int out_size, void* d_ws, size_t ws_size,
                              hipStream_t stream){
    const float* v0      = (const float*)d_in[0];
    const float* v1      = (const float*)d_in[1];
    const float* v2      = (const float*)d_in[2];
    const float* rel_pos = (const float*)d_in[3];
    const float* norms   = (const float*)d_in[4];
    const float* Wr0     = (const float*)d_in[5];
    const float* Wr1     = (const float*)d_in[6];
    const float* Wr2     = (const float*)d_in[7];
    const float* Wn0     = (const float*)d_in[8];
    const float* Wn1     = (const float*)d_in[9];
    const float* Wn2     = (const float*)d_in[10];
    float* out = (float*)d_out;
    float* ws  = (float*)d_ws;

    float* cg    = ws + 0;        // 615 (pad 640)
    float* wrsum = ws + 640;      // 7680
    float* sphx  = ws + 8320;     // 4096*9 = 36864
    float* relm  = ws + 45184;    // 4096*144 = 589824
    float* nlm   = ws + 635008;   // 4096*144 = 589824 (becomes verts after k_norm)
    float* ss    = ws + 1224832;  // 8

    hipMemsetAsync(ss, 0, 8 * sizeof(float), stream);
    k_cg<<<1, 64, 0, stream>>>(cg);
    k_wrsum<<<30, 256, 0, stream>>>(Wr0, Wr1, Wr2, wrsum);
    k_sphx<<<NB*NN, 64, 0, stream>>>(rel_pos, sphx);

    for (int layer = 0; layer < 2; ++layer){
        const float *p0, *p1, *p2; int s0, s1, s2;
        if (layer == 0){ p0 = v0; s0 = 16; p1 = v1; s1 = 48; p2 = v2; s2 = 80; }
        else           { p0 = nlm; s0 = 144; p1 = nlm + 16; s1 = 144; p2 = nlm + 64; s2 = 144; }
        k_rel<<<NB*NN, 64, 0, stream>>>(p0, p1, p2, s0, s1, s2, sphx, cg, wrsum + layer*3840, relm);
        k_mpnl<<<NB*NN, 64, 0, stream>>>(norms, relm, cg, Wn0, Wn1, Wn2, layer, nlm, ss + layer*4);
        k_norm<<<NB*NN, 64, 0, stream>>>(nlm, ss + layer*4, out, layer);
    }
}

// Round 2
// 266.925 us; speedup vs baseline: 2.1468x; 2.1468x over previous
//
#include <hip/hip_runtime.h>

#define NB 32
#define NN 128

// 15 (l, pair) entries in reference order:
// l=0: (0,0),(1,1),(2,2)
// l=1: (0,1),(1,0),(1,1),(1,2),(2,1),(2,2)
// l=2: (0,2),(1,1),(1,2),(2,0),(2,1),(2,2)
__constant__ int E_l [15] = {0,0,0, 1,1,1,1,1,1, 2,2,2,2,2,2};
__constant__ int E_l1[15] = {0,1,2, 0,1,1,1,2,2, 0,1,1,2,2,2};
__constant__ int E_l2[15] = {0,1,2, 1,0,1,2,1,2, 2,1,2,0,1,2};
__constant__ int E_cg[15] = {0,1,10, 35,44,53,80,125,170, 245,270,315,390,415,490};
__constant__ int E_t [15] = {0,16,32, 48,96,144,192,240,288, 336,416,496,576,656,736};

__device__ __forceinline__ double dfact(int n){
    const double F[9] = {1.0,1.0,2.0,6.0,24.0,120.0,720.0,5040.0,40320.0};
    return F[n];
}

__device__ float cg_single(int j1,int m1,int j2,int m2,int j,int m){
    if (m1 + m2 != m) return 0.0f;
    double pre = sqrt((2.0*j+1.0)*dfact(j+j1-j2)*dfact(j-j1+j2)*dfact(j1+j2-j)/dfact(j1+j2+j+1));
    pre *= sqrt(dfact(j+m)*dfact(j-m)*dfact(j1-m1)*dfact(j1+m1)*dfact(j2-m2)*dfact(j2+m2));
    int k0 = 0;
    if (j2-j-m1 > k0) k0 = j2-j-m1;
    if (j1+m2-j > k0) k0 = j1+m2-j;
    int k1 = j1+j2-j;
    if (j1-m1 < k1) k1 = j1-m1;
    if (j2+m2 < k1) k1 = j2+m2;
    double s = 0.0;
    for (int k = k0; k <= k1; ++k){
        double d = dfact(k)*dfact(j1+j2-j-k)*dfact(j1-m1-k)*dfact(j2+m2-k)*dfact(j-j2+m1+k)*dfact(j-j1-m2+k);
        s += ((k & 1) ? -1.0 : 1.0) / d;
    }
    return (float)(pre * s);
}

// Build CG table + per-T-entry decode tables in LDS.
// tb1 packs: c(4) | k(3)<<4 | dl(3)<<7 | d2(3)<<10 | mc(3)<<13 | ab(3)<<16 | sb(3)<<19 | (u0+2)(4)<<22
// tb2 = E_cg[e] + k   (coeff index = tb2 + (m*d2+u)*dl)
__device__ __forceinline__ void build_tables(float* CG, const float* cgT,
                                             unsigned* tb1, unsigned short* tb2,
                                             int t, int nthreads){
    for (int i = t; i < 615; i += nthreads) CG[i] = cgT[i];
    for (int idx = t; idx < 816; idx += nthreads){
        int e = 0;
        while (e < 14 && idx >= E_t[e+1]) e++;
        int l = E_l[e], l1 = E_l1[e], l2 = E_l2[e];
        int local = idx - E_t[e];
        int c = local & 15, k = local >> 4;
        int dl = 2*l+1, d2 = 2*l2+1, mc = 2*l1+1;
        int ab = (l1==0?0:(l1==1?1:4));
        int sb = (l2==0?0:(l2==1?1:4));
        int u0 = k - l + l1 + l2;                 // u index at m=0; u(m)=u0-m
        tb1[idx] = (unsigned)c | (unsigned)(k<<4) | (unsigned)(dl<<7) | (unsigned)(d2<<10)
                 | (unsigned)(mc<<13) | (unsigned)(ab<<16) | (unsigned)(sb<<19)
                 | (unsigned)((u0+2)<<22);
        tb2[idx] = (unsigned short)(E_cg[e] + k);
    }
}

// Fused setup: block 0 -> CG table to global + zero ss; blocks 1..30 -> wrsum; blocks 31+ -> sphx
__global__ __launch_bounds__(256) void k_setup(const float* __restrict__ rel_pos,
                                               const float* __restrict__ Wr0, const float* __restrict__ Wr1,
                                               const float* __restrict__ Wr2,
                                               float* __restrict__ cg, float* __restrict__ wrsum,
                                               float* __restrict__ sphx, float* __restrict__ ss){
    int bx = blockIdx.x;
    int t = threadIdx.x;
    if (bx == 0){
        if (t < 8) ss[t] = 0.f;
        for (int idx = t; idx < 615; idx += 256){
            int e = 0;
            while (e < 14 && idx >= E_cg[e+1]) e++;
            int l = E_l[e], l1 = E_l1[e], l2 = E_l2[e];
            int local = idx - E_cg[e];
            int dl = 2*l+1, d2 = 2*l2+1;
            int k  = local % dl;
            int r  = local / dl;
            int u  = r % d2;
            int i1 = r / d2;
            cg[idx] = cg_single(l1, i1-l1, l2, u-l2, l, k-l);
        }
        return;
    }
    if (bx <= 30){
        int q = (bx-1)*256 + t;   // 7680 total
        int layer = q / 3840;
        int r = q % 3840;
        int row = r / 16, co = r % 16;
        const float* Wr; int pairs; int lrow;
        if (row < 48)       { Wr = Wr0; pairs = 3; lrow = row; }
        else if (row < 144) { Wr = Wr1; pairs = 6; lrow = row - 48; }
        else                { Wr = Wr2; pairs = 6; lrow = row - 144; }
        int pairIdx = lrow / 16, c = lrow % 16;
        const float* base = Wr + (size_t)layer * pairs * 256 * 16 + (size_t)(pairIdx*256 + c*16) * 16 + co;
        float s = 0.f;
        #pragma unroll
        for (int d = 0; d < 16; ++d) s += base[d * 16];
        wrsum[q] = s;
        return;
    }
    // sphx: 4 nodes per block, wave per node
    int node = (bx - 31)*4 + (t >> 6);
    int lane = t & 63;
    const float* rp = rel_pos + (size_t)node * NN * 3;
    float acc[9];
    #pragma unroll
    for (int i = 0; i < 9; ++i) acc[i] = 0.f;
    for (int j = lane; j < NN; j += 64){
        float x = rp[j*3+0], y = rp[j*3+1], z = rp[j*3+2];
        float r = sqrtf(x*x + y*y + z*z) + 1e-6f;
        x /= r; y /= r; z /= r;
        acc[0] += 0.28209479f;
        acc[1] += 0.48860251f * y;
        acc[2] += 0.48860251f * z;
        acc[3] += 0.48860251f * x;
        acc[4] += 1.09254843f * x * y;
        acc[5] += 1.09254843f * y * z;
        acc[6] += 0.31539157f * (3.f * z * z - 1.f);
        acc[7] += 1.09254843f * x * z;
        acc[8] += 0.54627422f * (x*x - y*y);
    }
    #pragma unroll
    for (int i = 0; i < 9; ++i){
        float v = acc[i];
        for (int off = 32; off; off >>= 1) v += __shfl_down(v, off, 64);
        if (lane == 0) sphx[node*9 + i] = v;
    }
}

// k_rel: 4 nodes per block (wave per node). T via sparse CG, mix via transposed W in LDS.
__global__ __launch_bounds__(256) void k_rel(const float* __restrict__ p0, const float* __restrict__ p1,
                                             const float* __restrict__ p2, int s0, int s1, int s2,
                                             const float* __restrict__ sphx, const float* __restrict__ cgT,
                                             const float* __restrict__ wrsumL, float* __restrict__ rel){
    __shared__ float CG[615];
    __shared__ unsigned tb1[816];
    __shared__ unsigned short tb2[816];
    __shared__ float WT[16*244];     // transposed wrsum: WT[co*244 + row], row<240
    __shared__ float AL[4][144];
    __shared__ float SL[4][9];
    __shared__ float Tws[4][816];
    int t = threadIdx.x;
    int w = t >> 6, lane = t & 63;
    int node0 = blockIdx.x * 4;
    build_tables(CG, cgT, tb1, tb2, t, 256);
    for (int i = t; i < 3840; i += 256){
        int row = i >> 4, co = i & 15;
        WT[co*244 + row] = wrsumL[i];
    }
    for (int i = t; i < 4*144; i += 256){
        int n = i / 144, o = i % 144;
        int node = node0 + n;
        float v;
        if (o < 16)      v = p0[(size_t)node*s0 + o];
        else if (o < 64) v = p1[(size_t)node*s1 + (o-16)];
        else             v = p2[(size_t)node*s2 + (o-64)];
        AL[n][o] = v;
    }
    for (int i = t; i < 36; i += 256) SL[i/9][i%9] = sphx[(size_t)(node0 + i/9)*9 + i%9];
    __syncthreads();
    // T for this wave's node
    for (int idx = lane; idx < 816; idx += 64){
        unsigned p = tb1[idx];
        int c = p & 15, k = (p>>4)&7, dl=(p>>7)&7, d2=(p>>10)&7, mc=(p>>13)&7, ab=(p>>16)&7, sb=(p>>19)&7;
        int u0 = (int)((p>>22)&15) - 2;
        int cgb = tb2[idx];
        float s = 0.f;
        for (int m = 0; m < mc; ++m){
            int u = u0 - m;
            if (u >= 0 && u < d2)
                s += AL[w][(ab+m)*16 + c] * SL[w][sb+u] * CG[cgb + (m*d2+u)*dl];
        }
        Tws[w][idx] = s;
    }
    __syncthreads();
    // mix
    for (int o = lane; o < 144; o += 64){
        int krow = o >> 4, co = o & 15;
        int l = krow == 0 ? 0 : (krow < 4 ? 1 : 2);
        int k = krow - (l==0?0:(l==1?1:4));
        int np = l==0?3:6;
        int tbo = l==0?0:(l==1?48:336);
        int rb = l==0?0:(l==1?48:144);
        int dl = 2*l+1;
        float acc = 0.f;
        const float4* Wrow = (const float4*)&WT[co*244 + rb];
        for (int pq = 0; pq < np; ++pq){
            const float4* Tp = (const float4*)&Tws[w][tbo + (pq*dl + k)*16];
            float4 w0 = Wrow[pq*4+0], w1 = Wrow[pq*4+1], w2 = Wrow[pq*4+2], w3 = Wrow[pq*4+3];
            float4 t0 = Tp[0], t1 = Tp[1], t2 = Tp[2], t3 = Tp[3];
            acc += t0.x*w0.x + t0.y*w0.y + t0.z*w0.z + t0.w*w0.w;
            acc += t1.x*w1.x + t1.y*w1.y + t1.z*w1.z + t1.w*w1.w;
            acc += t2.x*w2.x + t2.y*w2.y + t2.z*w2.z + t2.w*w2.w;
            acc += t3.x*w3.x + t3.y*w3.y + t3.z*w3.z + t3.w*w3.w;
        }
        rel[(size_t)(node0 + w)*144 + o] = acc;
    }
}

// k_mpnl: 4 nodes per block. Message-pass via LDS-staged rel chunks (coalesced, shared by 4 waves),
// then diag CG product + Wn mix + ss atomics.
__global__ __launch_bounds__(256) void k_mpnl(const float* __restrict__ norms, const float* __restrict__ rel,
                                              const float* __restrict__ cgT,
                                              const float* __restrict__ Wn0, const float* __restrict__ Wn1,
                                              const float* __restrict__ Wn2,
                                              int layer, float* __restrict__ nl, float* __restrict__ ss){
    __shared__ float CG[615];
    __shared__ unsigned tb1[816];
    __shared__ unsigned short tb2[816];
    __shared__ float WT[16*244];     // transposed Wn concat: rows 0..47 l0, 48..143 l1, 144..239 l2
    __shared__ float c4[4][128];
    __shared__ float Srel[16*144];
    __shared__ float mpL[4][144];
    __shared__ float Tws[4][816];
    __shared__ float red[3][4];
    int t = threadIdx.x;
    int w = t >> 6, lane = t & 63;
    int node0 = blockIdx.x * 4;
    int b = node0 >> 7;
    build_tables(CG, cgT, tb1, tb2, t, 256);
    // Wn transposed cache
    for (int i = t; i < 768; i += 256){ int row = i>>4, co = i&15; WT[co*244 + row] = Wn0[(size_t)layer*768 + i]; }
    for (int i = t; i < 1536; i += 256){ int row = 48 + (i>>4), co = i&15; WT[co*244 + row] = Wn1[(size_t)layer*1536 + i]; }
    for (int i = t; i < 1536; i += 256){ int row = 144 + (i>>4), co = i&15; WT[co*244 + row] = Wn2[(size_t)layer*1536 + i]; }
    for (int i = t; i < 512; i += 256){
        int n = i >> 7, j = i & 127;
        c4[n][j] = (norms[(size_t)(node0+n)*NN + j] < 0.5f) ? 1.f : 0.f;
    }
    // message pass: stage rel in 16-row chunks
    float acc0 = 0.f, acc1 = 0.f, acc2 = 0.f;
    const float* relb = rel + (size_t)b * NN * 144;
    for (int jc = 0; jc < 8; ++jc){
        __syncthreads();
        const float4* r4 = (const float4*)(relb + (size_t)jc*16*144);
        float4* s4 = (float4*)Srel;
        for (int i = t; i < 576; i += 256) s4[i] = r4[i];
        __syncthreads();
        #pragma unroll 4
        for (int jj = 0; jj < 16; ++jj){
            float cn = c4[w][jc*16 + jj];
            acc0 += cn * Srel[jj*144 + lane];
            acc1 += cn * Srel[jj*144 + lane + 64];
            if (lane < 16) acc2 += cn * Srel[jj*144 + lane + 128];
        }
    }
    mpL[w][lane] = acc0;
    mpL[w][lane+64] = acc1;
    if (lane < 16) mpL[w][lane+128] = acc2;
    __syncthreads();
    // diag CG product
    for (int idx = lane; idx < 816; idx += 64){
        unsigned p = tb1[idx];
        int c = p & 15, k = (p>>4)&7, dl=(p>>7)&7, d2=(p>>10)&7, mc=(p>>13)&7, ab=(p>>16)&7, sb=(p>>19)&7;
        int u0 = (int)((p>>22)&15) - 2;
        int cgb = tb2[idx];
        float s = 0.f;
        for (int m = 0; m < mc; ++m){
            int u = u0 - m;
            if (u >= 0 && u < d2)
                s += mpL[w][(ab+m)*16 + c] * mpL[w][(sb+u)*16 + c] * CG[cgb + (m*d2+u)*dl];
        }
        Tws[w][idx] = s;
    }
    __syncthreads();
    // mix + ss partials
    float pz0 = 0.f, pz1 = 0.f, pz2 = 0.f;
    for (int o = lane; o < 144; o += 64){
        int krow = o >> 4, co = o & 15;
        int l = krow == 0 ? 0 : (krow < 4 ? 1 : 2);
        int k = krow - (l==0?0:(l==1?1:4));
        int np = l==0?3:6;
        int tbo = l==0?0:(l==1?48:336);
        int rb = l==0?0:(l==1?48:144);
        int dl = 2*l+1;
        float acc = 0.f;
        const float4* Wrow = (const float4*)&WT[co*244 + rb];
        for (int pq = 0; pq < np; ++pq){
            const float4* Tp = (const float4*)&Tws[w][tbo + (pq*dl + k)*16];
            float4 w0 = Wrow[pq*4+0], w1 = Wrow[pq*4+1], w2 = Wrow[pq*4+2], w3 = Wrow[pq*4+3];
            float4 t0 = Tp[0], t1 = Tp[1], t2 = Tp[2], t3 = Tp[3];
            acc += t0.x*w0.x + t0.y*w0.y + t0.z*w0.z + t0.w*w0.w;
            acc += t1.x*w1.x + t1.y*w1.y + t1.z*w1.z + t1.w*w1.w;
            acc += t2.x*w2.x + t2.y*w2.y + t2.z*w2.z + t2.w*w2.w;
            acc += t3.x*w3.x + t3.y*w3.y + t3.z*w3.z + t3.w*w3.w;
        }
        nl[(size_t)(node0 + w)*144 + o] = acc;
        float sq = acc * acc;
        if (l == 0) pz0 += sq; else if (l == 1) pz1 += sq; else pz2 += sq;
    }
    for (int off = 32; off; off >>= 1){
        pz0 += __shfl_down(pz0, off, 64);
        pz1 += __shfl_down(pz1, off, 64);
        pz2 += __shfl_down(pz2, off, 64);
    }
    if (lane == 0){ red[0][w] = pz0; red[1][w] = pz1; red[2][w] = pz2; }
    __syncthreads();
    if (t < 3){
        float s = red[t][0] + red[t][1] + red[t][2] + red[t][3];
        atomicAdd(&ss[t], s);
    }
}

// Normalize in place and emit scalars for this layer
__global__ __launch_bounds__(64) void k_norm(float* __restrict__ nl, const float* __restrict__ ss,
                                             float* __restrict__ out, int layer){
    __shared__ float vv[144];
    __shared__ float sc[3];
    int node = blockIdx.x;
    int t = threadIdx.x;
    if (t < 3) sc[t] = 16.f / ((2*t + 1) * sqrtf(ss[t]));
    __syncthreads();
    for (int i = t; i < 144; i += 64){
        int krow = i >> 4;
        int l = krow == 0 ? 0 : (krow < 4 ? 1 : 2);
        float v = nl[(size_t)node*144 + i] * sc[l];
        vv[i] = v;
        nl[(size_t)node*144 + i] = v;
    }
    __syncthreads();
    if (t < 16){
        int c = t;
        float s0 = vv[c];
        float sn0 = s0 * s0;
        float sn1 = 0.f;
        #pragma unroll
        for (int k = 0; k < 3; ++k){ float v = vv[16 + k*16 + c]; sn1 += v*v; }
        float sn2 = 0.f;
        #pragma unroll
        for (int k = 0; k < 5; ++k){ float v = vv[64 + k*16 + c]; sn2 += v*v; }
        float* ob = out + (size_t)node * 128 + layer * 64;
        ob[c]      = s0;
        ob[16 + c] = sn0;
        ob[32 + c] = sn1;
        ob[48 + c] = sn2;
    }
}

extern "C" void kernel_launch(void* const* d_in, const int* in_sizes, int n_in,
                              void* d_out, int out_size, void* d_ws, size_t ws_size,
                              hipStream_t stream){
    const float* v0      = (const float*)d_in[0];
    const float* v1      = (const float*)d_in[1];
    const float* v2      = (const float*)d_in[2];
    const float* rel_pos = (const float*)d_in[3];
    const float* norms   = (const float*)d_in[4];
    const float* Wr0     = (const float*)d_in[5];
    const float* Wr1     = (const float*)d_in[6];
    const float* Wr2     = (const float*)d_in[7];
    const float* Wn0     = (const float*)d_in[8];
    const float* Wn1     = (const float*)d_in[9];
    const float* Wn2     = (const float*)d_in[10];
    float* out = (float*)d_out;
    float* ws  = (float*)d_ws;

    float* cg    = ws + 0;        // 615 (pad 640)
    float* wrsum = ws + 640;      // 7680
    float* sphx  = ws + 8320;     // 4096*9 = 36864
    float* relm  = ws + 45184;    // 4096*144 = 589824
    float* nlm   = ws + 635008;   // 4096*144 = 589824
    float* ss    = ws + 1224832;  // 8

    k_setup<<<31 + NB*NN/4, 256, 0, stream>>>(rel_pos, Wr0, Wr1, Wr2, cg, wrsum, sphx, ss);

    for (int layer = 0; layer < 2; ++layer){
        const float *p0, *p1, *p2; int s0, s1, s2;
        if (layer == 0){ p0 = v0; s0 = 16; p1 = v1; s1 = 48; p2 = v2; s2 = 80; }
        else           { p0 = nlm; s0 = 144; p1 = nlm + 16; s1 = 144; p2 = nlm + 64; s2 = 144; }
        k_rel<<<NB*NN/4, 256, 0, stream>>>(p0, p1, p2, s0, s1, s2, sphx, cg, wrsum + layer*3840, relm);
        k_mpnl<<<NB*NN/4, 256, 0, stream>>>(norms, relm, cg, Wn0, Wn1, Wn2, layer, nlm, ss + layer*4);
        k_norm<<<NB*NN, 64, 0, stream>>>(nlm, ss + layer*4, out, layer);
    }
}